// Round 4
// baseline (81.730 us; speedup 1.0000x reference)
//
#include <hip/hip_runtime.h>
#include <hip/hip_bf16.h>

// Sizes fixed by the reference: B=16, N=2048, F_in=F_out=64.
#define NB 16
#define NN 2048
#define NF 64
#define LOG2E 1.44269504f
#define ISPLIT 16         // k_colsum i-split factor

typedef __attribute__((ext_vector_type(8))) __bf16 bf16x8;
typedef __attribute__((ext_vector_type(8))) short  short8;
typedef __attribute__((ext_vector_type(4))) float  f32x4;

// g(t) = exp(sigmoid(leakyrelu(t))), evaluated from pre-scaled tp = -log2e * t.
// In the negated-scaled domain, leaky becomes: u = min(tp, 0.2*tp)
__device__ __forceinline__ float evalg(float tp) {
    float u  = fminf(tp, 0.2f * tp);
    float ex = __builtin_amdgcn_exp2f(u);              // e^{-leaky}
    float s  = __builtin_amdgcn_rcpf(1.f + ex);        // sigmoid(leaky)
    return __builtin_amdgcn_exp2f(s * LOG2E);          // e^{sigmoid}
}

__device__ __forceinline__ float elu(float v) {
    return v > 0.f ? v : (__builtin_amdgcn_exp2f(v * LOG2E) - 1.f);
}

// ---------------- Pass A: Wh = h@W ; xs = -log2e*(Wh@a1) ; ys = -log2e*(Wh@a2)
__global__ __launch_bounds__(256) void k_prep(const float* __restrict__ h,
                                              const float* __restrict__ W,
                                              const float* __restrict__ a,
                                              float* __restrict__ wh,
                                              float* __restrict__ xs,
                                              float* __restrict__ ys) {
    __shared__ float hb[4][64];
    int w = threadIdx.x >> 6, lane = threadIdx.x & 63;
    int r = blockIdx.x * 4 + w;                 // row in [0, B*N)
    hb[w][lane] = h[r * 64 + lane];
    float acc = 0.f;
#pragma unroll
    for (int k = 0; k < 64; k++) acc = fmaf(hb[w][k], W[k * 64 + lane], acc);
    wh[r * 64 + lane] = acc;
    float xv = acc * a[lane];
    float yv = acc * a[64 + lane];
#pragma unroll
    for (int m = 32; m; m >>= 1) {
        xv += __shfl_xor(xv, m, 64);
        yv += __shfl_xor(yv, m, 64);
    }
    if (lane == 0) {
        xs[r] = -LOG2E * xv;
        ys[r] = -LOG2E * yv;
    }
}

// ---------------- Pass B: column-sum partials  dpart[isp][b][j] = sum over 128 i's of g(x_i+y_j)
__global__ __launch_bounds__(256) void k_colsum(const float* __restrict__ xs,
                                                const float* __restrict__ ys,
                                                float* __restrict__ dpart) {
    __shared__ float xb[128];
    int tid = threadIdx.x;
    int bx  = blockIdx.x;
    int jb  = bx & 7;            // N/256 = 8 j-chunks
    int isp = (bx >> 3) & 15;    // 16-way i split (128 i's each)
    int b   = bx >> 7;
    if (tid < 128) xb[tid] = xs[b * NN + isp * 128 + tid];
    __syncthreads();
    float yv  = ys[b * NN + jb * 256 + tid];
    float acc = 0.f;
#pragma unroll 4
    for (int i4 = 0; i4 < 32; i4++) {
        float4 xv = *reinterpret_cast<const float4*>(&xb[i4 * 4]);
        acc += evalg(xv.x + yv);
        acc += evalg(xv.y + yv);
        acc += evalg(xv.z + yv);
        acc += evalg(xv.w + yv);
    }
    dpart[isp * (NB * NN) + b * NN + jb * 256 + tid] = acc;
}

// ---------------- Pass B2 (fused D-reduce + V-frag): block per (b, ks) handles 32 rows.
// D[row] = sum of 16 dpart slices; V = Wh / D -> bf16 in MFMA B-fragment order.
// vfrag layout: [b][ks(64)][nt(4)][lane(64)] x 8 bf16; B-frag: col = lane&15, k = (lane>>4)*8 + e
__global__ __launch_bounds__(256) void k_vfragD(const float* __restrict__ wh,
                                                const float* __restrict__ dpart,
                                                uint4* __restrict__ vfrag) {
    __shared__ float pred[8][32];
    __shared__ float dinv[32];
    int bx = blockIdx.x;
    int ks = bx & 63;
    int b  = bx >> 6;
    int t  = threadIdx.x;
    {   // stage 1: 16 partials -> 8 in LDS
        int p = t >> 5, r = t & 31;
        int rowg = b * NN + ks * 32 + r;
        pred[p][r] = dpart[p * (NB * NN) + rowg] + dpart[(p + 8) * (NB * NN) + rowg];
    }
    __syncthreads();
    if (t < 32) {   // stage 2: finish the sum, invert
        float s = 0.f;
#pragma unroll
        for (int p2 = 0; p2 < 8; p2++) s += pred[p2][t];
        dinv[t] = __builtin_amdgcn_rcpf(s);
    }
    __syncthreads();
    int lane = t & 63, nt = t >> 6;
    int kg = lane >> 4, il = lane & 15;
    const float* whp = wh + (b * NN + ks * 32 + kg * 8) * 64 + nt * 16 + il;
    short8 o;
#pragma unroll
    for (int e = 0; e < 8; e++) {
        float v   = whp[e * 64] * dinv[kg * 8 + e];
        __bf16 bv = (__bf16)v;
        o[e]      = __builtin_bit_cast(short, bv);
    }
    vfrag[((b * 64 + ks) * 4 + nt) * 64 + lane] = __builtin_bit_cast(uint4, o);
}

// ---------------- Pass C: out = ELU( E @ V ), fused via in-block K-split.
// Block = 256 threads = 4 waves; block owns 16 output rows; wave kz handles 16 K-steps.
// Waves 1..3 dump f32 accs to LDS; wave 0 reduces + ELU + stores.
// A-frag (16x32): row = lane&15, k = (lane>>4)*8 + e
// C/D frag:       col = lane&15, row = (lane>>4)*4 + reg   [verified layout]
__global__ __launch_bounds__(256, 8) void k_attn(const float* __restrict__ xs,
                                                 const float* __restrict__ ys,
                                                 const uint4* __restrict__ vfrag,
                                                 float* __restrict__ out) {
    __shared__ float red[3][16][65];   // [kz-1][local row][col(+pad)]
    int b  = blockIdx.x >> 7;          // batch
    int ib = blockIdx.x & 127;         // 128 i-blocks of 16 rows
    int kz = threadIdx.x >> 6, lane = threadIdx.x & 63;
    int il = lane & 15, kg = lane >> 4;
    int ibase = ib * 16;

    float xv = xs[b * NN + ibase + il];
    const float* ysb = ys + b * NN;
    const uint4* vfb = vfrag + b * 16384 + lane;

    f32x4 acc0 = {0.f, 0.f, 0.f, 0.f};
    f32x4 acc1 = {0.f, 0.f, 0.f, 0.f};
    f32x4 acc2 = {0.f, 0.f, 0.f, 0.f};
    f32x4 acc3 = {0.f, 0.f, 0.f, 0.f};

    for (int ks = kz * 16; ks < kz * 16 + 16; ks++) {
        const float* yp = ysb + ks * 32 + kg * 8;
        float4 ya = *reinterpret_cast<const float4*>(yp);
        float4 yb = *reinterpret_cast<const float4*>(yp + 4);
        float wv[8];
        wv[0] = evalg(xv + ya.x);
        wv[1] = evalg(xv + ya.y);
        wv[2] = evalg(xv + ya.z);
        wv[3] = evalg(xv + ya.w);
        wv[4] = evalg(xv + yb.x);
        wv[5] = evalg(xv + yb.y);
        wv[6] = evalg(xv + yb.z);
        wv[7] = evalg(xv + yb.w);
        bf16x8 af;
#pragma unroll
        for (int e = 0; e < 8; e++) af[e] = (__bf16)wv[e];

        const uint4* vp = vfb + ks * 256;
        bf16x8 b0 = __builtin_bit_cast(bf16x8, vp[0]);
        bf16x8 b1 = __builtin_bit_cast(bf16x8, vp[64]);
        bf16x8 b2 = __builtin_bit_cast(bf16x8, vp[128]);
        bf16x8 b3 = __builtin_bit_cast(bf16x8, vp[192]);

        acc0 = __builtin_amdgcn_mfma_f32_16x16x32_bf16(af, b0, acc0, 0, 0, 0);
        acc1 = __builtin_amdgcn_mfma_f32_16x16x32_bf16(af, b1, acc1, 0, 0, 0);
        acc2 = __builtin_amdgcn_mfma_f32_16x16x32_bf16(af, b2, acc2, 0, 0, 0);
        acc3 = __builtin_amdgcn_mfma_f32_16x16x32_bf16(af, b3, acc3, 0, 0, 0);
    }

    if (kz > 0) {
#pragma unroll
        for (int r = 0; r < 4; r++) {
            float* rp = &red[kz - 1][kg * 4 + r][il];
            rp[0]  = acc0[r];
            rp[16] = acc1[r];
            rp[32] = acc2[r];
            rp[48] = acc3[r];
        }
    }
    __syncthreads();
    if (kz == 0) {
        int rbase = b * NN + ibase + kg * 4;
#pragma unroll
        for (int r = 0; r < 4; r++) {
            const float* r0 = &red[0][kg * 4 + r][il];
            const float* r1 = &red[1][kg * 4 + r][il];
            const float* r2 = &red[2][kg * 4 + r][il];
            float* orow = out + (rbase + r) * 64 + il;
            orow[0]  = elu(acc0[r] + r0[0]  + r1[0]  + r2[0]);
            orow[16] = elu(acc1[r] + r0[16] + r1[16] + r2[16]);
            orow[32] = elu(acc2[r] + r0[32] + r1[32] + r2[32]);
            orow[48] = elu(acc3[r] + r0[48] + r1[48] + r2[48]);
        }
    }
}

extern "C" void kernel_launch(void* const* d_in, const int* in_sizes, int n_in,
                              void* d_out, int out_size, void* d_ws, size_t ws_size,
                              hipStream_t stream) {
    const float* h = (const float*)d_in[0];
    const float* W = (const float*)d_in[1];
    const float* a = (const float*)d_in[2];
    float* out = (float*)d_out;

    // workspace layout (floats), ~15 MB total
    float* wh    = (float*)d_ws;                   // B*N*64   = 2,097,152 f
    float* xs    = wh + NB * NN * NF;              // B*N      =    32,768 f
    float* ys    = xs + NB * NN;                   // B*N
    float* dpart = ys + NB * NN;                   // 16*B*N   =   524,288 f
    uint4* vfrag = (uint4*)(dpart + ISPLIT * NB * NN);  // B*N*64 bf16 = 4 MB

    k_prep<<<dim3(NB * NN / 4), dim3(256), 0, stream>>>(h, W, a, wh, xs, ys);
    k_colsum<<<dim3(NB * ISPLIT * (NN / 256)), dim3(256), 0, stream>>>(xs, ys, dpart);
    k_vfragD<<<dim3(NB * 64), dim3(256), 0, stream>>>(wh, dpart, vfrag);
    k_attn<<<dim3(NB * (NN / 16)), dim3(256), 0, stream>>>(xs, ys, vfrag, out);
}

// Round 5
// 74.881 us; speedup vs baseline: 1.0915x; 1.0915x over previous
//
#include <hip/hip_runtime.h>
#include <hip/hip_bf16.h>
#include <math.h>

// Sizes fixed by the reference: B=16, N=2048, F_in=F_out=64.
#define NB 16
#define NN 2048
#define NF 64
#define LOG2E 1.44269504f
#define ISPLIT 16         // k_colsum i-split factor

// g(t) lookup table: t in [T_LO, T_HI], NT bins, linear interpolation.
#define NT 2048
#define T_LO (-40.0f)
#define T_HI (10.0f)
#define T_SCALE (NT / (T_HI - T_LO))         // 40.96 bins per unit t
#define Z_BIAS (-T_LO * T_SCALE)             // 1638.4
#define Z_MAX (NT - 1.001f)

typedef __attribute__((ext_vector_type(8))) __bf16 bf16x8;
typedef __attribute__((ext_vector_type(8))) short  short8;
typedef __attribute__((ext_vector_type(4))) float  f32x4;

// Accurate g(t) = exp(sigmoid(leakyrelu(t))) — used only to build the table (2k evals).
__device__ __forceinline__ float gexact(float t) {
    float v = t >= 0.f ? t : 0.2f * t;
    float s = 1.f / (1.f + expf(-v));
    return expf(s);
}

// Table lookup: z = t*T_SCALE + Z_BIAS (caller pre-folds the scale/bias into operands).
__device__ __forceinline__ float tlookup(const float2* __restrict__ stab, float z) {
    z = fminf(fmaxf(z, 0.f), Z_MAX);
    int   idx = (int)z;                 // z >= 0, trunc == floor
    float fr  = z - (float)idx;
    float2 e  = stab[idx];
    return fmaf(e.y, fr, e.x);
}

__device__ __forceinline__ float elu(float v) {
    return v > 0.f ? v : (__builtin_amdgcn_exp2f(v * LOG2E) - 1.f);
}

// ---------------- Pass A: Wh = h@W ; xs = T_SCALE*(Wh@a1) ; ys = T_SCALE*(Wh@a2)
// Blocks 0..7 additionally build the g-table (one entry per thread).
__global__ __launch_bounds__(256) void k_prep(const float* __restrict__ h,
                                              const float* __restrict__ W,
                                              const float* __restrict__ a,
                                              float* __restrict__ wh,
                                              float* __restrict__ xs,
                                              float* __restrict__ ys,
                                              float2* __restrict__ gtab) {
    __shared__ float hb[4][64];
    int w = threadIdx.x >> 6, lane = threadIdx.x & 63;
    int r = blockIdx.x * 4 + w;                 // row in [0, B*N)
    hb[w][lane] = h[r * 64 + lane];
    float acc = 0.f;
#pragma unroll
    for (int k = 0; k < 64; k++) acc = fmaf(hb[w][k], W[k * 64 + lane], acc);
    wh[r * 64 + lane] = acc;
    float xv = acc * a[lane];
    float yv = acc * a[64 + lane];
#pragma unroll
    for (int m = 32; m; m >>= 1) {
        xv += __shfl_xor(xv, m, 64);
        yv += __shfl_xor(yv, m, 64);
    }
    if (lane == 0) {
        xs[r] = T_SCALE * xv;
        ys[r] = T_SCALE * yv;
    }
    if (blockIdx.x < 8) {
        int i = blockIdx.x * 256 + threadIdx.x;     // [0, 2048)
        float t0 = T_LO + (float)i / T_SCALE;
        float t1 = T_LO + (float)(i + 1) / T_SCALE;
        float g0 = gexact(t0);
        gtab[i] = make_float2(g0, gexact(t1) - g0);
    }
}

// ---------------- Pass B: column-sum partials  dpart[isp][b][j] = sum over 128 i's of g(x_i+y_j)
__global__ __launch_bounds__(256) void k_colsum(const float* __restrict__ xs,
                                                const float* __restrict__ ys,
                                                const float2* __restrict__ gtab,
                                                float* __restrict__ dpart) {
    __shared__ float2 stab[NT];
    __shared__ float  xb[128];
    int tid = threadIdx.x;
    {   // stage table (16 KB) into LDS
        const float4* src = (const float4*)gtab;
        float4*       dst = (float4*)stab;
#pragma unroll
        for (int k = 0; k < NT / 2 / 256; k++) dst[tid + k * 256] = src[tid + k * 256];
    }
    int bx  = blockIdx.x;
    int jb  = bx & 7;            // N/256 = 8 j-chunks
    int isp = (bx >> 3) & 15;    // 16-way i split (128 i's each)
    int b   = bx >> 7;
    if (tid < 128) xb[tid] = xs[b * NN + isp * 128 + tid];
    __syncthreads();
    float ypre = ys[b * NN + jb * 256 + tid] + Z_BIAS;
    float acc = 0.f;
#pragma unroll 4
    for (int i4 = 0; i4 < 32; i4++) {
        float4 xv = *reinterpret_cast<const float4*>(&xb[i4 * 4]);
        acc += tlookup(stab, xv.x + ypre);
        acc += tlookup(stab, xv.y + ypre);
        acc += tlookup(stab, xv.z + ypre);
        acc += tlookup(stab, xv.w + ypre);
    }
    dpart[isp * (NB * NN) + b * NN + jb * 256 + tid] = acc;
}

// ---------------- Pass B2 (fused D-reduce + V-frag): block per (b, ks) handles 32 rows.
// D[row] = sum of 16 dpart slices; V = Wh / D -> bf16 in MFMA B-fragment order.
// vfrag layout: [b][ks(64)][nt(4)][lane(64)] x 8 bf16; B-frag: col = lane&15, k = (lane>>4)*8 + e
__global__ __launch_bounds__(256) void k_vfragD(const float* __restrict__ wh,
                                                const float* __restrict__ dpart,
                                                uint4* __restrict__ vfrag) {
    __shared__ float pred[8][32];
    __shared__ float dinv[32];
    int bx = blockIdx.x;
    int ks = bx & 63;
    int b  = bx >> 6;
    int t  = threadIdx.x;
    {   // stage 1: 16 partials -> 8 in LDS
        int p = t >> 5, r = t & 31;
        int rowg = b * NN + ks * 32 + r;
        pred[p][r] = dpart[p * (NB * NN) + rowg] + dpart[(p + 8) * (NB * NN) + rowg];
    }
    __syncthreads();
    if (t < 32) {   // stage 2: finish the sum, invert
        float s = 0.f;
#pragma unroll
        for (int p2 = 0; p2 < 8; p2++) s += pred[p2][t];
        dinv[t] = __builtin_amdgcn_rcpf(s);
    }
    __syncthreads();
    int lane = t & 63, nt = t >> 6;
    int kg = lane >> 4, il = lane & 15;
    const float* whp = wh + (b * NN + ks * 32 + kg * 8) * 64 + nt * 16 + il;
    short8 o;
#pragma unroll
    for (int e = 0; e < 8; e++) {
        float v   = whp[e * 64] * dinv[kg * 8 + e];
        __bf16 bv = (__bf16)v;
        o[e]      = __builtin_bit_cast(short, bv);
    }
    vfrag[((b * 64 + ks) * 4 + nt) * 64 + lane] = __builtin_bit_cast(uint4, o);
}

// ---------------- Pass C: out = ELU( E @ V ), fused via in-block K-split.
// Block = 256 threads = 4 waves; block owns 16 output rows; wave kz handles 16 K-steps.
// Waves 1..3 dump f32 accs to LDS; wave 0 reduces + ELU + stores.
// A-frag (16x32): row = lane&15, k = (lane>>4)*8 + e
// C/D frag:       col = lane&15, row = (lane>>4)*4 + reg   [verified layout]
__global__ __launch_bounds__(256) void k_attn(const float* __restrict__ xs,
                                              const float* __restrict__ ys,
                                              const float2* __restrict__ gtab,
                                              const uint4* __restrict__ vfrag,
                                              float* __restrict__ out) {
    __shared__ float2 stab[NT];
    __shared__ float  red[3][16][65];   // [kz-1][local row][col(+pad)]
    {   // stage table (16 KB) into LDS
        const float4* src = (const float4*)gtab;
        float4*       dst = (float4*)stab;
#pragma unroll
        for (int k = 0; k < NT / 2 / 256; k++) dst[threadIdx.x + k * 256] = src[threadIdx.x + k * 256];
    }
    int b  = blockIdx.x >> 7;          // batch
    int ib = blockIdx.x & 127;         // 128 i-blocks of 16 rows
    int kz = threadIdx.x >> 6, lane = threadIdx.x & 63;
    int il = lane & 15, kg = lane >> 4;
    int ibase = ib * 16;

    float xv = xs[b * NN + ibase + il] + Z_BIAS;
    const float* ysb = ys + b * NN;
    const uint4* vfb = vfrag + b * 16384 + lane;
    __syncthreads();

    f32x4 acc0 = {0.f, 0.f, 0.f, 0.f};
    f32x4 acc1 = {0.f, 0.f, 0.f, 0.f};
    f32x4 acc2 = {0.f, 0.f, 0.f, 0.f};
    f32x4 acc3 = {0.f, 0.f, 0.f, 0.f};

    for (int ks = kz * 16; ks < kz * 16 + 16; ks++) {
        const float* yp = ysb + ks * 32 + kg * 8;
        float4 ya = *reinterpret_cast<const float4*>(yp);
        float4 yb = *reinterpret_cast<const float4*>(yp + 4);
        float wv[8];
        wv[0] = tlookup(stab, xv + ya.x);
        wv[1] = tlookup(stab, xv + ya.y);
        wv[2] = tlookup(stab, xv + ya.z);
        wv[3] = tlookup(stab, xv + ya.w);
        wv[4] = tlookup(stab, xv + yb.x);
        wv[5] = tlookup(stab, xv + yb.y);
        wv[6] = tlookup(stab, xv + yb.z);
        wv[7] = tlookup(stab, xv + yb.w);
        bf16x8 af;
#pragma unroll
        for (int e = 0; e < 8; e++) af[e] = (__bf16)wv[e];

        const uint4* vp = vfb + ks * 256;
        bf16x8 b0 = __builtin_bit_cast(bf16x8, vp[0]);
        bf16x8 b1 = __builtin_bit_cast(bf16x8, vp[64]);
        bf16x8 b2 = __builtin_bit_cast(bf16x8, vp[128]);
        bf16x8 b3 = __builtin_bit_cast(bf16x8, vp[192]);

        acc0 = __builtin_amdgcn_mfma_f32_16x16x32_bf16(af, b0, acc0, 0, 0, 0);
        acc1 = __builtin_amdgcn_mfma_f32_16x16x32_bf16(af, b1, acc1, 0, 0, 0);
        acc2 = __builtin_amdgcn_mfma_f32_16x16x32_bf16(af, b2, acc2, 0, 0, 0);
        acc3 = __builtin_amdgcn_mfma_f32_16x16x32_bf16(af, b3, acc3, 0, 0, 0);
    }

    if (kz > 0) {
#pragma unroll
        for (int r = 0; r < 4; r++) {
            float* rp = &red[kz - 1][kg * 4 + r][il];
            rp[0]  = acc0[r];
            rp[16] = acc1[r];
            rp[32] = acc2[r];
            rp[48] = acc3[r];
        }
    }
    __syncthreads();
    if (kz == 0) {
        int rbase = b * NN + ibase + kg * 4;
#pragma unroll
        for (int r = 0; r < 4; r++) {
            const float* r0 = &red[0][kg * 4 + r][il];
            const float* r1 = &red[1][kg * 4 + r][il];
            const float* r2 = &red[2][kg * 4 + r][il];
            float* orow = out + (rbase + r) * 64 + il;
            orow[0]  = elu(acc0[r] + r0[0]  + r1[0]  + r2[0]);
            orow[16] = elu(acc1[r] + r0[16] + r1[16] + r2[16]);
            orow[32] = elu(acc2[r] + r0[32] + r1[32] + r2[32]);
            orow[48] = elu(acc3[r] + r0[48] + r1[48] + r2[48]);
        }
    }
}

extern "C" void kernel_launch(void* const* d_in, const int* in_sizes, int n_in,
                              void* d_out, int out_size, void* d_ws, size_t ws_size,
                              hipStream_t stream) {
    const float* h = (const float*)d_in[0];
    const float* W = (const float*)d_in[1];
    const float* a = (const float*)d_in[2];
    float* out = (float*)d_out;

    // workspace layout (floats), ~15 MB total
    float*  wh    = (float*)d_ws;                  // B*N*64   = 2,097,152 f
    float*  xs    = wh + NB * NN * NF;             // B*N      =    32,768 f
    float*  ys    = xs + NB * NN;                  // B*N
    float*  dpart = ys + NB * NN;                  // 16*B*N   =   524,288 f
    uint4*  vfrag = (uint4*)(dpart + ISPLIT * NB * NN);  // B*N*64 bf16 = 4 MB
    float2* gtab  = (float2*)(vfrag + NB * NN * NF / 8); // 2048 float2 = 16 KB

    k_prep<<<dim3(NB * NN / 4), dim3(256), 0, stream>>>(h, W, a, wh, xs, ys, gtab);
    k_colsum<<<dim3(NB * ISPLIT * (NN / 256)), dim3(256), 0, stream>>>(xs, ys, gtab, dpart);
    k_vfragD<<<dim3(NB * 64), dim3(256), 0, stream>>>(wh, dpart, vfrag);
    k_attn<<<dim3(NB * (NN / 16)), dim3(256), 0, stream>>>(xs, ys, gtab, vfrag, out);
}

// Round 7
// 70.880 us; speedup vs baseline: 1.1531x; 1.0564x over previous
//
#include <hip/hip_runtime.h>
#include <hip/hip_bf16.h>
#include <math.h>

// Sizes fixed by the reference: B=16, N=2048, F_in=F_out=64.
#define NB 16
#define NN 2048
#define NF 64
#define LOG2E 1.44269504f
#define ISPLIT 16         // k_colsum i-split factor

// g(t) lookup table: t in [T_LO, T_HI], NT bins, linear interpolation.
#define NT 2048
#define T_LO (-40.0f)
#define T_HI (10.0f)
#define T_SCALE (NT / (T_HI - T_LO))         // 40.96 bins per unit t
#define Z_BIAS (-T_LO * T_SCALE)             // 1638.4
#define Z_MAX (NT - 1.001f)

typedef __attribute__((ext_vector_type(8))) __bf16 bf16x8;
typedef __attribute__((ext_vector_type(8))) short  short8;
typedef __attribute__((ext_vector_type(4))) float  f32x4;

// Accurate g(t) = exp(sigmoid(leakyrelu(t))) — used only to build the table (2k evals).
__device__ __forceinline__ float gexact(float t) {
    float v = t >= 0.f ? t : 0.2f * t;
    float s = 1.f / (1.f + expf(-v));
    return expf(s);
}

// Table lookup: z = t*T_SCALE + Z_BIAS (caller pre-folds the scale/bias into operands).
__device__ __forceinline__ float tlookup(const float2* __restrict__ stab, float z) {
    float zc  = __builtin_amdgcn_fmed3f(z, 0.f, Z_MAX);
    int   idx = (int)zc;                // zc >= 0, trunc == floor
    float fr  = zc - (float)idx;
    float2 e  = stab[idx];
    return fmaf(e.y, fr, e.x);
}

__device__ __forceinline__ float elu(float v) {
    return v > 0.f ? v : (__builtin_amdgcn_exp2f(v * LOG2E) - 1.f);
}

// ---------------- Pass A: Wh = h@W ; xs = T_SCALE*(Wh@a1) ; ys = T_SCALE*(Wh@a2)
// Blocks 0..7 additionally build the g-table (one entry per thread).
__global__ __launch_bounds__(256) void k_prep(const float* __restrict__ h,
                                              const float* __restrict__ W,
                                              const float* __restrict__ a,
                                              float* __restrict__ wh,
                                              float* __restrict__ xs,
                                              float* __restrict__ ys,
                                              float2* __restrict__ gtab) {
    __shared__ float hb[4][64];
    int w = threadIdx.x >> 6, lane = threadIdx.x & 63;
    int r = blockIdx.x * 4 + w;                 // row in [0, B*N)
    hb[w][lane] = h[r * 64 + lane];
    float acc = 0.f;
#pragma unroll
    for (int k = 0; k < 64; k++) acc = fmaf(hb[w][k], W[k * 64 + lane], acc);
    wh[r * 64 + lane] = acc;
    float xv = acc * a[lane];
    float yv = acc * a[64 + lane];
#pragma unroll
    for (int m = 32; m; m >>= 1) {
        xv += __shfl_xor(xv, m, 64);
        yv += __shfl_xor(yv, m, 64);
    }
    if (lane == 0) {
        xs[r] = T_SCALE * xv;
        ys[r] = T_SCALE * yv;
    }
    if (blockIdx.x < 8) {
        int i = blockIdx.x * 256 + threadIdx.x;     // [0, 2048)
        float t0 = T_LO + (float)i / T_SCALE;
        float t1 = T_LO + (float)(i + 1) / T_SCALE;
        float g0 = gexact(t0);
        gtab[i] = make_float2(g0, gexact(t1) - g0);
    }
}

// ---------------- Pass B: column-sum partials  dpart[isp][b][j] = sum over 128 i's of g(x_i+y_j)
__global__ __launch_bounds__(256) void k_colsum(const float* __restrict__ xs,
                                                const float* __restrict__ ys,
                                                const float2* __restrict__ gtab,
                                                float* __restrict__ dpart) {
    __shared__ float2 stab[NT];
    __shared__ float  xb[128];
    int tid = threadIdx.x;
    {   // stage table (16 KB) into LDS
        const float4* src = (const float4*)gtab;
        float4*       dst = (float4*)stab;
#pragma unroll
        for (int k = 0; k < NT / 2 / 256; k++) dst[tid + k * 256] = src[tid + k * 256];
    }
    int bx  = blockIdx.x;
    int jb  = bx & 7;            // N/256 = 8 j-chunks
    int isp = (bx >> 3) & 15;    // 16-way i split (128 i's each)
    int b   = bx >> 7;
    if (tid < 128) xb[tid] = xs[b * NN + isp * 128 + tid];
    __syncthreads();
    float ypre = ys[b * NN + jb * 256 + tid] + Z_BIAS;
    float acc = 0.f;
#pragma unroll 4
    for (int i4 = 0; i4 < 32; i4++) {
        float4 xv = *reinterpret_cast<const float4*>(&xb[i4 * 4]);
        acc += tlookup(stab, xv.x + ypre);
        acc += tlookup(stab, xv.y + ypre);
        acc += tlookup(stab, xv.z + ypre);
        acc += tlookup(stab, xv.w + ypre);
    }
    dpart[isp * (NB * NN) + b * NN + jb * 256 + tid] = acc;
}

// ---------------- Pass B2 (fused D-reduce + V-frag): block per (b, ks) handles 32 rows.
// D[row] = sum of 16 dpart slices; V = Wh / D -> bf16 in MFMA B-fragment order.
// vfrag layout: [b][ks(64)][nt(4)][lane(64)] x 8 bf16; B-frag: col = lane&15, k = (lane>>4)*8 + e
__global__ __launch_bounds__(256) void k_vfragD(const float* __restrict__ wh,
                                                const float* __restrict__ dpart,
                                                uint4* __restrict__ vfrag) {
    __shared__ float pred[8][32];
    __shared__ float dinv[32];
    int bx = blockIdx.x;
    int ks = bx & 63;
    int b  = bx >> 6;
    int t  = threadIdx.x;
    {   // stage 1: 16 partials -> 8 in LDS
        int p = t >> 5, r = t & 31;
        int rowg = b * NN + ks * 32 + r;
        pred[p][r] = dpart[p * (NB * NN) + rowg] + dpart[(p + 8) * (NB * NN) + rowg];
    }
    __syncthreads();
    if (t < 32) {   // stage 2: finish the sum, invert
        float s = 0.f;
#pragma unroll
        for (int p2 = 0; p2 < 8; p2++) s += pred[p2][t];
        dinv[t] = __builtin_amdgcn_rcpf(s);
    }
    __syncthreads();
    int lane = t & 63, nt = t >> 6;
    int kg = lane >> 4, il = lane & 15;
    const float* whp = wh + (b * NN + ks * 32 + kg * 8) * 64 + nt * 16 + il;
    short8 o;
#pragma unroll
    for (int e = 0; e < 8; e++) {
        float v   = whp[e * 64] * dinv[kg * 8 + e];
        __bf16 bv = (__bf16)v;
        o[e]      = __builtin_bit_cast(short, bv);
    }
    vfrag[((b * 64 + ks) * 4 + nt) * 64 + lane] = __builtin_bit_cast(uint4, o);
}

// ---------------- Pass C: out = ELU( E @ V ), 32 rows per block for V-reuse.
// Block = 256 threads = 4 waves: wave w -> (rg = w&1, kz = w>>1).
// Wave (rg,kz) computes rows [ib*32+rg*16, +16) over K-steps [kz*32, +32).
// The two rg-waves of a kz-slice load identical V fragments (L1 hit).
// kz=1 waves dump accs to LDS; kz=0 waves add + ELU + store.
// A-frag (16x32): row = lane&15, k = (lane>>4)*8 + e
// C/D frag:       col = lane&15, row = (lane>>4)*4 + reg   [verified layout]
__global__ __launch_bounds__(256) void k_attn(const float* __restrict__ xs,
                                              const float* __restrict__ ys,
                                              const float2* __restrict__ gtab,
                                              const uint4* __restrict__ vfrag,
                                              float* __restrict__ out) {
    __shared__ float2 stab[NT];
    __shared__ float  red[2][16][65];   // [rg][local row][col(+pad)]
    {   // stage table (16 KB) into LDS
        const float4* src = (const float4*)gtab;
        float4*       dst = (float4*)stab;
#pragma unroll
        for (int k = 0; k < NT / 2 / 256; k++) dst[threadIdx.x + k * 256] = src[threadIdx.x + k * 256];
    }
    int b  = blockIdx.x >> 6;          // batch
    int ib = blockIdx.x & 63;          // 64 i-blocks of 32 rows
    int w  = threadIdx.x >> 6, lane = threadIdx.x & 63;
    int rg = w & 1, kz = w >> 1;
    int il = lane & 15, kg = lane >> 4;
    int ibase = ib * 32 + rg * 16;

    float xv = xs[b * NN + ibase + il] + Z_BIAS;
    const float* ysb = ys + b * NN;
    const uint4* vfb = vfrag + b * 16384 + lane;
    __syncthreads();

    f32x4 acc0 = {0.f, 0.f, 0.f, 0.f};
    f32x4 acc1 = {0.f, 0.f, 0.f, 0.f};
    f32x4 acc2 = {0.f, 0.f, 0.f, 0.f};
    f32x4 acc3 = {0.f, 0.f, 0.f, 0.f};

    for (int ks = kz * 32; ks < kz * 32 + 32; ks++) {
        const float* yp = ysb + ks * 32 + kg * 8;
        float4 ya = *reinterpret_cast<const float4*>(yp);
        float4 yb = *reinterpret_cast<const float4*>(yp + 4);
        float wv[8];
        wv[0] = tlookup(stab, xv + ya.x);
        wv[1] = tlookup(stab, xv + ya.y);
        wv[2] = tlookup(stab, xv + ya.z);
        wv[3] = tlookup(stab, xv + ya.w);
        wv[4] = tlookup(stab, xv + yb.x);
        wv[5] = tlookup(stab, xv + yb.y);
        wv[6] = tlookup(stab, xv + yb.z);
        wv[7] = tlookup(stab, xv + yb.w);
        bf16x8 af;
#pragma unroll
        for (int e = 0; e < 8; e++) af[e] = (__bf16)wv[e];

        const uint4* vp = vfb + ks * 256;
        bf16x8 b0 = __builtin_bit_cast(bf16x8, vp[0]);
        bf16x8 b1 = __builtin_bit_cast(bf16x8, vp[64]);
        bf16x8 b2 = __builtin_bit_cast(bf16x8, vp[128]);
        bf16x8 b3 = __builtin_bit_cast(bf16x8, vp[192]);

        acc0 = __builtin_amdgcn_mfma_f32_16x16x32_bf16(af, b0, acc0, 0, 0, 0);
        acc1 = __builtin_amdgcn_mfma_f32_16x16x32_bf16(af, b1, acc1, 0, 0, 0);
        acc2 = __builtin_amdgcn_mfma_f32_16x16x32_bf16(af, b2, acc2, 0, 0, 0);
        acc3 = __builtin_amdgcn_mfma_f32_16x16x32_bf16(af, b3, acc3, 0, 0, 0);
    }

    if (kz == 1) {
#pragma unroll
        for (int r = 0; r < 4; r++) {
            float* rp = &red[rg][kg * 4 + r][il];
            rp[0]  = acc0[r];
            rp[16] = acc1[r];
            rp[32] = acc2[r];
            rp[48] = acc3[r];
        }
    }
    __syncthreads();
    if (kz == 0) {
        int rbase = b * NN + ibase + kg * 4;
#pragma unroll
        for (int r = 0; r < 4; r++) {
            const float* r0 = &red[rg][kg * 4 + r][il];
            float* orow = out + (rbase + r) * 64 + il;
            orow[0]  = elu(acc0[r] + r0[0]);
            orow[16] = elu(acc1[r] + r0[16]);
            orow[32] = elu(acc2[r] + r0[32]);
            orow[48] = elu(acc3[r] + r0[48]);
        }
    }
}

extern "C" void kernel_launch(void* const* d_in, const int* in_sizes, int n_in,
                              void* d_out, int out_size, void* d_ws, size_t ws_size,
                              hipStream_t stream) {
    const float* h = (const float*)d_in[0];
    const float* W = (const float*)d_in[1];
    const float* a = (const float*)d_in[2];
    float* out = (float*)d_out;

    // workspace layout (floats), ~15 MB total
    float*  wh    = (float*)d_ws;                  // B*N*64   = 2,097,152 f
    float*  xs    = wh + NB * NN * NF;             // B*N      =    32,768 f
    float*  ys    = xs + NB * NN;                  // B*N
    float*  dpart = ys + NB * NN;                  // 16*B*N   =   524,288 f
    uint4*  vfrag = (uint4*)(dpart + ISPLIT * NB * NN);  // B*N*64 bf16 = 4 MB
    float2* gtab  = (float2*)(vfrag + NB * NN * NF / 8); // 2048 float2 = 16 KB

    k_prep<<<dim3(NB * NN / 4), dim3(256), 0, stream>>>(h, W, a, wh, xs, ys, gtab);
    k_colsum<<<dim3(NB * ISPLIT * (NN / 256)), dim3(256), 0, stream>>>(xs, ys, gtab, dpart);
    k_vfragD<<<dim3(NB * 64), dim3(256), 0, stream>>>(wh, dpart, vfrag);
    k_attn<<<dim3(NB * (NN / 32)), dim3(256), 0, stream>>>(xs, ys, gtab, vfrag, out);
}

// Round 8
// 70.484 us; speedup vs baseline: 1.1596x; 1.0056x over previous
//
#include <hip/hip_runtime.h>
#include <hip/hip_bf16.h>
#include <math.h>

// Sizes fixed by the reference: B=16, N=2048, F_in=F_out=64.
#define NB 16
#define NN 2048
#define NF 64
#define LOG2E 1.44269504f
#define ISPLIT 16         // k_colsum i-split factor

// g(t) nearest-neighbor table: t in [T_LO, T_HI], NT bins, value at bin midpoint.
#define NT 4096
#define T_LO (-40.0f)
#define T_HI (10.0f)
#define T_SCALE (NT / (T_HI - T_LO))         // 81.92 bins per unit t
#define Z_BIAS (-T_LO * T_SCALE)             // 3276.8
#define Z_MAX ((float)(NT - 1))

typedef __attribute__((ext_vector_type(8))) __bf16 bf16x8;
typedef __attribute__((ext_vector_type(8))) short  short8;
typedef __attribute__((ext_vector_type(4))) float  f32x4;

// Accurate g(t) = exp(sigmoid(leakyrelu(t))) — used only to build the table (4k evals).
__device__ __forceinline__ float gexact(float t) {
    float v = t >= 0.f ? t : 0.2f * t;
    float s = 1.f / (1.f + expf(-v));
    return expf(s);
}

// NN table lookup: z = t*T_SCALE + Z_BIAS (scale/bias pre-folded by caller).
__device__ __forceinline__ float tlookup(const float* __restrict__ stab, float z) {
    float zc = __builtin_amdgcn_fmed3f(z, 0.f, Z_MAX);
    return stab[(int)zc];
}

__device__ __forceinline__ float elu(float v) {
    return v > 0.f ? v : (__builtin_amdgcn_exp2f(v * LOG2E) - 1.f);
}

// ---------------- Pass A: Wh = h@W ; xs = T_SCALE*(Wh@a1) ; ys = T_SCALE*(Wh@a2)
// Blocks 0..15 additionally build the g-table (one midpoint entry per thread).
__global__ __launch_bounds__(256) void k_prep(const float* __restrict__ h,
                                              const float* __restrict__ W,
                                              const float* __restrict__ a,
                                              float* __restrict__ wh,
                                              float* __restrict__ xs,
                                              float* __restrict__ ys,
                                              float* __restrict__ gtab) {
    __shared__ float hb[4][64];
    int w = threadIdx.x >> 6, lane = threadIdx.x & 63;
    int r = blockIdx.x * 4 + w;                 // row in [0, B*N)
    hb[w][lane] = h[r * 64 + lane];
    float acc = 0.f;
#pragma unroll
    for (int k = 0; k < 64; k++) acc = fmaf(hb[w][k], W[k * 64 + lane], acc);
    wh[r * 64 + lane] = acc;
    float xv = acc * a[lane];
    float yv = acc * a[64 + lane];
#pragma unroll
    for (int m = 32; m; m >>= 1) {
        xv += __shfl_xor(xv, m, 64);
        yv += __shfl_xor(yv, m, 64);
    }
    if (lane == 0) {
        xs[r] = T_SCALE * xv;
        ys[r] = T_SCALE * yv;
    }
    if (blockIdx.x < 16) {
        int i = blockIdx.x * 256 + threadIdx.x;     // [0, 4096)
        gtab[i] = gexact(T_LO + ((float)i + 0.5f) / T_SCALE);
    }
}

// ---------------- Pass B: column-sum partials  dpart[isp][b][j] = sum over 128 i's of g(x_i+y_j)
__global__ __launch_bounds__(256) void k_colsum(const float* __restrict__ xs,
                                                const float* __restrict__ ys,
                                                const float* __restrict__ gtab,
                                                float* __restrict__ dpart) {
    __shared__ float stab[NT];
    __shared__ float xb[128];
    int tid = threadIdx.x;
    {   // stage table (16 KB) into LDS
        const float4* src = (const float4*)gtab;
        float4*       dst = (float4*)stab;
#pragma unroll
        for (int k = 0; k < NT / 4 / 256; k++) dst[tid + k * 256] = src[tid + k * 256];
    }
    int bx  = blockIdx.x;
    int jb  = bx & 7;            // N/256 = 8 j-chunks
    int isp = (bx >> 3) & 15;    // 16-way i split (128 i's each)
    int b   = bx >> 7;
    if (tid < 128) xb[tid] = xs[b * NN + isp * 128 + tid];
    __syncthreads();
    float ypre = ys[b * NN + jb * 256 + tid] + Z_BIAS;
    float acc = 0.f;
#pragma unroll 4
    for (int i4 = 0; i4 < 32; i4++) {
        float4 xv = *reinterpret_cast<const float4*>(&xb[i4 * 4]);
        acc += tlookup(stab, xv.x + ypre);
        acc += tlookup(stab, xv.y + ypre);
        acc += tlookup(stab, xv.z + ypre);
        acc += tlookup(stab, xv.w + ypre);
    }
    dpart[isp * (NB * NN) + b * NN + jb * 256 + tid] = acc;
}

// ---------------- Pass B2 (fused D-reduce + V-frag): block per (b, ks) handles 32 rows.
// D[row] = sum of 16 dpart slices; V = Wh / D -> bf16 in MFMA B-fragment order.
// vfrag layout: [b][ks(64)][nt(4)][lane(64)] x 8 bf16; B-frag: col = lane&15, k = (lane>>4)*8 + e
__global__ __launch_bounds__(256) void k_vfragD(const float* __restrict__ wh,
                                                const float* __restrict__ dpart,
                                                uint4* __restrict__ vfrag) {
    __shared__ float pred[8][32];
    __shared__ float dinv[32];
    int bx = blockIdx.x;
    int ks = bx & 63;
    int b  = bx >> 6;
    int t  = threadIdx.x;
    {   // stage 1: 16 partials -> 8 in LDS
        int p = t >> 5, r = t & 31;
        int rowg = b * NN + ks * 32 + r;
        pred[p][r] = dpart[p * (NB * NN) + rowg] + dpart[(p + 8) * (NB * NN) + rowg];
    }
    __syncthreads();
    if (t < 32) {   // stage 2: finish the sum, invert
        float s = 0.f;
#pragma unroll
        for (int p2 = 0; p2 < 8; p2++) s += pred[p2][t];
        dinv[t] = __builtin_amdgcn_rcpf(s);
    }
    __syncthreads();
    int lane = t & 63, nt = t >> 6;
    int kg = lane >> 4, il = lane & 15;
    const float* whp = wh + (b * NN + ks * 32 + kg * 8) * 64 + nt * 16 + il;
    short8 o;
#pragma unroll
    for (int e = 0; e < 8; e++) {
        float v   = whp[e * 64] * dinv[kg * 8 + e];
        __bf16 bv = (__bf16)v;
        o[e]      = __builtin_bit_cast(short, bv);
    }
    vfrag[((b * 64 + ks) * 4 + nt) * 64 + lane] = __builtin_bit_cast(uint4, o);
}

// ---------------- Pass C: out = ELU( E @ V ), 32 rows per block for V-reuse.
// Block = 256 threads = 4 waves: wave w -> (rg = w&1, kz = w>>1).
// Wave (rg,kz) computes rows [ib*32+rg*16, +16) over K-steps [kz*32, +32).
// The two rg-waves of a kz-slice load identical V fragments (L1 hit).
// kz=1 waves dump accs to LDS; kz=0 waves add + ELU + store.
// A-frag (16x32): row = lane&15, k = (lane>>4)*8 + e
// C/D frag:       col = lane&15, row = (lane>>4)*4 + reg   [verified layout]
__global__ __launch_bounds__(256) void k_attn(const float* __restrict__ xs,
                                              const float* __restrict__ ys,
                                              const float* __restrict__ gtab,
                                              const uint4* __restrict__ vfrag,
                                              float* __restrict__ out) {
    __shared__ float stab[NT];
    __shared__ float red[2][16][65];   // [rg][local row][col(+pad)]
    {   // stage table (16 KB) into LDS
        const float4* src = (const float4*)gtab;
        float4*       dst = (float4*)stab;
#pragma unroll
        for (int k = 0; k < NT / 4 / 256; k++) dst[threadIdx.x + k * 256] = src[threadIdx.x + k * 256];
    }
    int b  = blockIdx.x >> 6;          // batch
    int ib = blockIdx.x & 63;          // 64 i-blocks of 32 rows
    int w  = threadIdx.x >> 6, lane = threadIdx.x & 63;
    int rg = w & 1, kz = w >> 1;
    int il = lane & 15, kg = lane >> 4;
    int ibase = ib * 32 + rg * 16;

    float xv = xs[b * NN + ibase + il] + Z_BIAS;
    const float* ysb = ys + b * NN;
    const uint4* vfb = vfrag + b * 16384 + lane;
    __syncthreads();

    f32x4 acc0 = {0.f, 0.f, 0.f, 0.f};
    f32x4 acc1 = {0.f, 0.f, 0.f, 0.f};
    f32x4 acc2 = {0.f, 0.f, 0.f, 0.f};
    f32x4 acc3 = {0.f, 0.f, 0.f, 0.f};

    for (int ks = kz * 32; ks < kz * 32 + 32; ks++) {
        const float* yp = ysb + ks * 32 + kg * 8;
        float4 ya = *reinterpret_cast<const float4*>(yp);
        float4 yb = *reinterpret_cast<const float4*>(yp + 4);
        float wv[8];
        wv[0] = tlookup(stab, xv + ya.x);
        wv[1] = tlookup(stab, xv + ya.y);
        wv[2] = tlookup(stab, xv + ya.z);
        wv[3] = tlookup(stab, xv + ya.w);
        wv[4] = tlookup(stab, xv + yb.x);
        wv[5] = tlookup(stab, xv + yb.y);
        wv[6] = tlookup(stab, xv + yb.z);
        wv[7] = tlookup(stab, xv + yb.w);
        bf16x8 af;
#pragma unroll
        for (int e = 0; e < 8; e++) af[e] = (__bf16)wv[e];

        const uint4* vp = vfb + ks * 256;
        bf16x8 b0 = __builtin_bit_cast(bf16x8, vp[0]);
        bf16x8 b1 = __builtin_bit_cast(bf16x8, vp[64]);
        bf16x8 b2 = __builtin_bit_cast(bf16x8, vp[128]);
        bf16x8 b3 = __builtin_bit_cast(bf16x8, vp[192]);

        acc0 = __builtin_amdgcn_mfma_f32_16x16x32_bf16(af, b0, acc0, 0, 0, 0);
        acc1 = __builtin_amdgcn_mfma_f32_16x16x32_bf16(af, b1, acc1, 0, 0, 0);
        acc2 = __builtin_amdgcn_mfma_f32_16x16x32_bf16(af, b2, acc2, 0, 0, 0);
        acc3 = __builtin_amdgcn_mfma_f32_16x16x32_bf16(af, b3, acc3, 0, 0, 0);
    }

    if (kz == 1) {
#pragma unroll
        for (int r = 0; r < 4; r++) {
            float* rp = &red[rg][kg * 4 + r][il];
            rp[0]  = acc0[r];
            rp[16] = acc1[r];
            rp[32] = acc2[r];
            rp[48] = acc3[r];
        }
    }
    __syncthreads();
    if (kz == 0) {
        int rbase = b * NN + ibase + kg * 4;
#pragma unroll
        for (int r = 0; r < 4; r++) {
            const float* r0 = &red[rg][kg * 4 + r][il];
            float* orow = out + (rbase + r) * 64 + il;
            orow[0]  = elu(acc0[r] + r0[0]);
            orow[16] = elu(acc1[r] + r0[16]);
            orow[32] = elu(acc2[r] + r0[32]);
            orow[48] = elu(acc3[r] + r0[48]);
        }
    }
}

extern "C" void kernel_launch(void* const* d_in, const int* in_sizes, int n_in,
                              void* d_out, int out_size, void* d_ws, size_t ws_size,
                              hipStream_t stream) {
    const float* h = (const float*)d_in[0];
    const float* W = (const float*)d_in[1];
    const float* a = (const float*)d_in[2];
    float* out = (float*)d_out;

    // workspace layout (floats), ~15 MB total
    float*  wh    = (float*)d_ws;                  // B*N*64   = 2,097,152 f
    float*  xs    = wh + NB * NN * NF;             // B*N      =    32,768 f
    float*  ys    = xs + NB * NN;                  // B*N
    float*  dpart = ys + NB * NN;                  // 16*B*N   =   524,288 f
    uint4*  vfrag = (uint4*)(dpart + ISPLIT * NB * NN);  // B*N*64 bf16 = 4 MB
    float*  gtab  = (float*)(vfrag + NB * NN * NF / 8);  // 4096 f32 = 16 KB

    k_prep<<<dim3(NB * NN / 4), dim3(256), 0, stream>>>(h, W, a, wh, xs, ys, gtab);
    k_colsum<<<dim3(NB * ISPLIT * (NN / 256)), dim3(256), 0, stream>>>(xs, ys, gtab, dpart);
    k_vfragD<<<dim3(NB * 64), dim3(256), 0, stream>>>(wh, dpart, vfrag);
    k_attn<<<dim3(NB * (NN / 32)), dim3(256), 0, stream>>>(xs, ys, gtab, vfrag, out);
}